// Round 3
// baseline (874.793 us; speedup 1.0000x reference)
//
#include <hip/hip_runtime.h>

// Elman RNN, SEQ=4096, BATCH=8192, HID=4, tanh, + fc(1) on last step.
// Latency-chain-bound: wall = 4096 * per-step serial chain. 4 lanes per batch
// element (lane h owns hidden unit h); state r = 1/(exp(2z)+1), h = 1-2r
// folded into pre-scaled weights; cross-lane h via DPP quad_perm.
//
// R1/R2 lesson: the occupancy-targeting scheduler sinks global prefetch loads
// to their uses (VGPR_Count 36 << ring size), putting ~900-cyc HBM latency on
// the serial chain (~35-40 stall cyc/step). Fix: stage x through LDS. One
// wave per block -> DS ops are wave-ordered, NO barriers. Per step the x read
// is a single ds_read_b32 with immediate offset (zero addr math); even if the
// scheduler sinks it, LDS latency (~60-120 cyc) is covered by one step of
// slack instead of 900.
constexpr int SEQ   = 4096;
constexpr int BATCH = 8192;
constexpr int CH    = 64;        // timesteps per LDS chunk
constexpr int NCH   = SEQ / CH;  // 64 chunks
constexpr int BPW   = 16;        // batch elements per wave

template <int CTRL>
__device__ __forceinline__ float qperm(float v) {
  int i = __builtin_bit_cast(int, v);
  i = __builtin_amdgcn_mov_dpp(i, CTRL, 0xF, 0xF, true);
  return __builtin_bit_cast(float, i);
}
// quad_perm: rot1 [1,2,3,0]=0x39, rot2 [2,3,0,1]=0x4E, rot3 [3,0,1,2]=0x93

__global__ __launch_bounds__(64, 1) void rnn_kernel(
    const float* __restrict__ x, const float* __restrict__ h0,
    const float* __restrict__ W_ih, const float* __restrict__ b_ih,
    const float* __restrict__ W_hh, const float* __restrict__ b_hh,
    const float* __restrict__ fc_W, const float* __restrict__ fc_b,
    float* __restrict__ out) {
  const int l = threadIdx.x;      // lane
  const int q = l >> 2;           // quad index = local batch element
  const int h = l & 3;            // hidden unit owned by this lane
  const int b = blockIdx.x * BPW + q;

  // p = 2*log2(e)*z so exp2(p) = e^{2z}; h_j = 1-2r_j folded into weights.
  const float L2E2 = 2.0f * 1.4426950408889634f;
  const float w_self = W_hh[h * 4 + h];
  const float w_a = W_hh[h * 4 + ((h + 1) & 3)];
  const float w_b = W_hh[h * 4 + ((h + 2) & 3)];
  const float w_c = W_hh[h * 4 + ((h + 3) & 3)];
  const float A  = L2E2 * W_ih[h];
  const float Bc = L2E2 * (b_ih[h] + b_hh[h] + w_self + w_a + w_b + w_c);
  const float Ws = -2.0f * L2E2 * w_self;
  const float Wa = -2.0f * L2E2 * w_a;
  const float Wb = -2.0f * L2E2 * w_b;
  const float Wc = -2.0f * L2E2 * w_c;

  float r = fmaf(-0.5f, h0[b * 4 + h], 0.5f);  // r = (1-h)/2

  // LDS: 2 chunks of [CH timesteps][BPW floats]  (4 KiB each).
  __shared__ alignas(16) float smem[2][CH * BPW];

  // Staging: lane l loads x[t0 + (l>>2)][bgrp + (l&3)*4 .. +3] as float4;
  // 4 such loads (t0 += 16) cover one 64-step chunk. LDS float4 slot
  // k*64 + l  ->  row t_local = k*16 + l/4, cols (l&3)*4.. , i.e. layout
  // [t_local][b_local] with 64 B rows. ds_write_b128 stride-1: conflict-free.
  const float* gsrc = x + (size_t)(l >> 2) * BATCH + blockIdx.x * BPW + (l & 3) * 4;

  float4 st[4];
  auto stage_load = [&](int chunk) {
#pragma unroll
    for (int k = 0; k < 4; ++k)
      st[k] = *(const float4*)(gsrc + ((size_t)chunk * CH + k * 16) * BATCH);
  };
  auto stage_write = [&](int half) {
    float4* dst = (float4*)smem[half];
#pragma unroll
    for (int k = 0; k < 4; ++k) dst[k * 64 + l] = st[k];
  };

  auto step = [&](float xv) {
    const float ra = qperm<0x39>(r);
    const float rb = qperm<0x4E>(r);
    const float rc = qperm<0x93>(r);
    const float c  = fmaf(xv, A, Bc);           // off critical path
    float t1 = fmaf(Ws, r, c);
    t1 = fmaf(Wa, ra, t1);
    const float t2 = fmaf(Wb, rb, Wc * rc);
    const float p = t1 + t2;
    const float e = __builtin_amdgcn_exp2f(p);  // e^{2z}
    r = __builtin_amdgcn_rcpf(e + 1.0f);
  };

  // Per-step x read: quad-broadcast ds_read_b32, immediate offset s*64.
  auto consume = [&](int half) {
    const float* cur = smem[half];
#pragma unroll
    for (int s = 0; s < CH; ++s) step(cur[s * BPW + q]);
  };

  stage_load(0);
  stage_write(0);                 // one-time vmcnt(0) stall, ~1 us total
  for (int c = 0; c < NCH - 1; ++c) {
    stage_load(c + 1);            // issued ~3000 cyc before its vmcnt wait
    consume(c & 1);
    stage_write((c + 1) & 1);     // DS in-order per wave: no barrier needed
  }
  consume((NCH - 1) & 1);

  const float hfin = fmaf(-2.0f, r, 1.0f);  // h = 1 - 2r
  out[BATCH + b * 4 + h] = hfin;            // hn: (1,BATCH,4) at offset BATCH
  float tsum = hfin * fc_W[h];              // y = fc(h_last): quad reduction
  tsum += qperm<0x39>(tsum);
  tsum += qperm<0x4E>(tsum);
  if (h == 0) out[b] = tsum + fc_b[0];
}

extern "C" void kernel_launch(void* const* d_in, const int* in_sizes, int n_in,
                              void* d_out, int out_size, void* d_ws, size_t ws_size,
                              hipStream_t stream) {
  const float* x    = (const float*)d_in[0];
  const float* h0   = (const float*)d_in[1];
  const float* W_ih = (const float*)d_in[2];
  const float* b_ih = (const float*)d_in[3];
  const float* W_hh = (const float*)d_in[4];
  const float* b_hh = (const float*)d_in[5];
  const float* fc_W = (const float*)d_in[6];
  const float* fc_b = (const float*)d_in[7];
  float* out = (float*)d_out;

  // 4 lanes per batch element -> 32768 threads; single-wave blocks (no
  // barriers), 512 blocks over 256 CUs.
  dim3 block(64);
  dim3 grid(BATCH * 4 / 64);  // 512 blocks
  rnn_kernel<<<grid, block, 0, stream>>>(x, h0, W_ih, b_ih, W_hh, b_hh, fc_W,
                                         fc_b, out);
}

// Round 4
// 296.596 us; speedup vs baseline: 2.9494x; 2.9494x over previous
//
#include <hip/hip_runtime.h>

// Elman RNN, SEQ=4096, BATCH=8192, HID=4, tanh, + fc(1) on last step.
// Latency-chain-bound: wall = 4096 * per-step serial chain (~36 cyc:
// dpp -> fma tree -> exp2 -> +1 -> rcp). 4 lanes per batch element; state
// r = 1/(exp(2z)+1), h = 1-2r folded into pre-scaled weights; cross-lane h
// exchange via DPP quad_perm.
//
// R1-R3 lesson: the pre-RA machine scheduler sinks/spills long-lived
// prefetch loads to shrink live ranges (R1: sunk, VGPR=56; R2: sunk,
// VGPR=36; R3: LDS path spilled, WRITE_SIZE 6 MB, lgkmcnt serialization).
// Fix: __builtin_amdgcn_sched_barrier(0) after every step+refill pair —
// loads stay pinned 2*U=32 steps (~1300 cyc) ahead of their use, so vmcnt
// waits land on returned data. Cross-step scheduling has no upside here
// (the chain is serial), so the fence costs nothing.
constexpr int SEQ   = 4096;
constexpr int BATCH = 8192;
constexpr int U     = 16;  // steps per buffer half

template <int CTRL>
__device__ __forceinline__ float qperm(float v) {
  int i = __builtin_bit_cast(int, v);
  i = __builtin_amdgcn_mov_dpp(i, CTRL, 0xF, 0xF, true);
  return __builtin_bit_cast(float, i);
}
// quad_perm: rot1 [1,2,3,0]=0x39, rot2 [2,3,0,1]=0x4E, rot3 [3,0,1,2]=0x93

__global__ __launch_bounds__(64, 1) void rnn_kernel(
    const float* __restrict__ x, const float* __restrict__ h0,
    const float* __restrict__ W_ih, const float* __restrict__ b_ih,
    const float* __restrict__ W_hh, const float* __restrict__ b_hh,
    const float* __restrict__ fc_W, const float* __restrict__ fc_b,
    float* __restrict__ out) {
  const int tid = blockIdx.x * 64 + threadIdx.x;
  const int b = tid >> 2;   // batch element
  const int h = tid & 3;    // hidden unit owned by this lane

  // p = 2*log2(e)*z so exp2(p) = e^{2z}; h_j = 1-2r_j folded into weights.
  const float L2E2 = 2.0f * 1.4426950408889634f;
  const float w_self = W_hh[h * 4 + h];
  const float w_a = W_hh[h * 4 + ((h + 1) & 3)];
  const float w_b = W_hh[h * 4 + ((h + 2) & 3)];
  const float w_c = W_hh[h * 4 + ((h + 3) & 3)];
  const float A  = L2E2 * W_ih[h];
  const float Bc = L2E2 * (b_ih[h] + b_hh[h] + w_self + w_a + w_b + w_c);
  const float Ws = -2.0f * L2E2 * w_self;
  const float Wa = -2.0f * L2E2 * w_a;
  const float Wb = -2.0f * L2E2 * w_b;
  const float Wc = -2.0f * L2E2 * w_c;

  float r = fmaf(-0.5f, h0[b * 4 + h], 0.5f);  // r = (1-h)/2

  // 32-bit element index of x[t][b]; SGPR base + voffset addressing,
  // one v_add_u32 per refill. Max index 4096*8192 < 2^31.
  unsigned idx = (unsigned)b;

  float bufA[U], bufB[U];
#pragma unroll
  for (int i = 0; i < U; ++i) { bufA[i] = x[idx]; idx += BATCH; }
#pragma unroll
  for (int i = 0; i < U; ++i) { bufB[i] = x[idx]; idx += BATCH; }
  __builtin_amdgcn_sched_barrier(0);

  auto step = [&](float xv) {
    const float ra = qperm<0x39>(r);
    const float rb = qperm<0x4E>(r);
    const float rc = qperm<0x93>(r);
    const float c  = fmaf(xv, A, Bc);           // off critical path
    float t1 = fmaf(Ws, r, c);
    t1 = fmaf(Wa, ra, t1);
    const float t2 = fmaf(Wb, rb, Wc * rc);
    const float p = t1 + t2;
    const float e = __builtin_amdgcn_exp2f(p);  // e^{2z}
    r = __builtin_amdgcn_rcpf(e + 1.0f);
  };

  // 2U steps per iteration; each step refills its slot 2U steps ahead and is
  // fenced so the scheduler cannot sink the load toward its use.
  for (int t0 = 0; t0 <= SEQ - 4 * U; t0 += 2 * U) {
#pragma unroll
    for (int i = 0; i < U; ++i) {
      step(bufA[i]);
      bufA[i] = x[idx]; idx += BATCH;
      __builtin_amdgcn_sched_barrier(0);
    }
#pragma unroll
    for (int i = 0; i < U; ++i) {
      step(bufB[i]);
      bufB[i] = x[idx]; idx += BATCH;
      __builtin_amdgcn_sched_barrier(0);
    }
  }
  // Epilogue: last 2U steps, buffers hold t = SEQ-2U .. SEQ-1.
#pragma unroll
  for (int i = 0; i < U; ++i) step(bufA[i]);
#pragma unroll
  for (int i = 0; i < U; ++i) step(bufB[i]);

  const float hfin = fmaf(-2.0f, r, 1.0f);  // h = 1 - 2r
  out[BATCH + b * 4 + h] = hfin;            // hn: (1,BATCH,4) at offset BATCH
  float tsum = hfin * fc_W[h];              // y = fc(h_last): quad reduction
  tsum += qperm<0x39>(tsum);
  tsum += qperm<0x4E>(tsum);
  if (h == 0) out[b] = tsum + fc_b[0];
}

extern "C" void kernel_launch(void* const* d_in, const int* in_sizes, int n_in,
                              void* d_out, int out_size, void* d_ws, size_t ws_size,
                              hipStream_t stream) {
  const float* x    = (const float*)d_in[0];
  const float* h0   = (const float*)d_in[1];
  const float* W_ih = (const float*)d_in[2];
  const float* b_ih = (const float*)d_in[3];
  const float* W_hh = (const float*)d_in[4];
  const float* b_hh = (const float*)d_in[5];
  const float* fc_W = (const float*)d_in[6];
  const float* fc_b = (const float*)d_in[7];
  float* out = (float*)d_out;

  // 4 lanes per batch element -> 32768 threads; single-wave blocks, 512
  // blocks over 256 CUs (2 waves/CU — batch parallelism is exhausted).
  dim3 block(64);
  dim3 grid(BATCH * 4 / 64);  // 512 blocks
  rnn_kernel<<<grid, block, 0, stream>>>(x, h0, W_ih, b_ih, W_hh, b_hh, fc_W,
                                         fc_b, out);
}